// Round 3
// baseline (3088.935 us; speedup 1.0000x reference)
//
#include <hip/hip_runtime.h>

#define DIM 128

__global__ __launch_bounds__(256) void deg_count(const int* __restrict__ dst,
                                                 float* __restrict__ deg, int ne) {
    int i = blockIdx.x * 256 + threadIdx.x;
    if (i < ne) atomicAdd(&deg[dst[i]], 1.0f);
}

__global__ __launch_bounds__(256) void make_norm(float* __restrict__ deg, int n) {
    int i = blockIdx.x * 256 + threadIdx.x;
    if (i < n) {
        float d = deg[i];
        deg[i] = rsqrtf(d > 1.0f ? d : 1.0f);
    }
}

// W is [out=128][in=128] fp32 row-major. Produce Wt laid out so that
// thread j can load float4 {W[j][k..k+3]} with consecutive-j coalescing:
//   Wt[(k>>2)*512 + j*4 + (k&3)] = W[j][k]
__global__ __launch_bounds__(256) void transpose_w(const float* __restrict__ W,
                                                   float* __restrict__ Wt) {
    int i = blockIdx.x * 256 + threadIdx.x; // 0..16383
    int j = i >> 7;
    int k = i & 127;
    Wt[(k >> 2) * 512 + j * 4 + (k & 3)] = W[i];
}

// 32 lanes per edge; each lane handles 4 features (float4 load, 4 fp32 atomics)
__global__ __launch_bounds__(256) void scatter(const float* __restrict__ h,
                                               const int* __restrict__ src,
                                               const int* __restrict__ dst,
                                               const float* __restrict__ norm,
                                               float* __restrict__ agg, int ne) {
    int lane = threadIdx.x & 31;
    int e = blockIdx.x * 8 + (threadIdx.x >> 5);
    if (e >= ne) return;
    int s = src[e];
    int d = dst[e];
    float sc = norm[s];
    float4 v = *(const float4*)(h + (size_t)s * DIM + lane * 4);
    float* p = agg + (size_t)d * DIM + lane * 4;
    atomicAdd(p + 0, v.x * sc);
    atomicAdd(p + 1, v.y * sc);
    atomicAdd(p + 2, v.z * sc);
    atomicAdd(p + 3, v.w * sc);
}

// Block = 256 threads handles 8 rows: half = tid>>7 picks rows [r0, r0+4),
// j = tid&127 is the output feature. out[r][j] = norm[r]*dot(agg[r],W[j]) + b[j]
__global__ __launch_bounds__(256) void rowgemm(const float* __restrict__ agg,
                                               const float* __restrict__ Wt,
                                               const float* __restrict__ b,
                                               const float* __restrict__ norm,
                                               float* __restrict__ out,
                                               int n) {
    int tid = threadIdx.x;
    int j = tid & 127;
    int half = tid >> 7;
    int r0 = blockIdx.x * 8 + half * 4; // n == 100000 divides by 8 exactly
    const float4* Wt4 = (const float4*)Wt;
    const float4* x4 = (const float4*)agg;

    float acc[4] = {0.f, 0.f, 0.f, 0.f};
    for (int k4 = 0; k4 < DIM / 4; ++k4) {
        float4 w = Wt4[k4 * 128 + j]; // coalesced across j
#pragma unroll
        for (int r = 0; r < 4; ++r) {
            float4 x = x4[(size_t)(r0 + r) * 32 + k4]; // wave-uniform address
            acc[r] += x.x * w.x + x.y * w.y + x.z * w.z + x.w * w.w;
        }
    }
    float bj = b[j];
#pragma unroll
    for (int r = 0; r < 4; ++r) {
        float nr = norm[r0 + r];
        out[(size_t)(r0 + r) * DIM + j] = acc[r] * nr + bj;
    }
}

extern "C" void kernel_launch(void* const* d_in, const int* in_sizes, int n_in,
                              void* d_out, int out_size, void* d_ws, size_t ws_size,
                              hipStream_t stream) {
    const float* h = (const float*)d_in[0];  // fp32 [N,128]
    const float* W = (const float*)d_in[1];  // fp32 [128,128]
    const float* b = (const float*)d_in[2];  // fp32 [128]
    const int* esrc = (const int*)d_in[3];
    const int* edst = (const int*)d_in[4];
    float* out = (float*)d_out;              // fp32 [N,128]

    int n = in_sizes[0] / DIM;   // 100000
    int ne = in_sizes[3];        // 1600000

    // ws layout: agg fp32 [N*128] | norm fp32 [N] | Wt fp32 [16384]
    float* agg = (float*)d_ws;
    float* norm = agg + (size_t)n * DIM;
    float* Wt = norm + n;

    hipMemsetAsync(agg, 0, (size_t)n * DIM * sizeof(float), stream);
    hipMemsetAsync(norm, 0, (size_t)n * sizeof(float), stream);

    deg_count<<<(ne + 255) / 256, 256, 0, stream>>>(edst, norm, ne);
    make_norm<<<(n + 255) / 256, 256, 0, stream>>>(norm, n);
    transpose_w<<<64, 256, 0, stream>>>(W, Wt);
    scatter<<<(ne + 7) / 8, 256, 0, stream>>>(h, esrc, edst, norm, agg, ne);
    rowgemm<<<(n + 7) / 8, 256, 0, stream>>>(agg, Wt, b, norm, out, n);
}

// Round 4
// 599.530 us; speedup vs baseline: 5.1523x; 5.1523x over previous
//
#include <hip/hip_runtime.h>

#define DIM 128

// ws layout: norm f32[n] | Wt f32[16384] | deg i32[n] | cursor i32[n] | ebuf i32[ne]
// total ~7.7 MB (well under the >=51.8 MB ws proven available in round 3)

__global__ __launch_bounds__(256) void deg_count(const int* __restrict__ dst,
                                                 int* __restrict__ deg, int ne) {
    int i = blockIdx.x * 256 + threadIdx.x;
    if (i < ne) atomicAdd(&deg[dst[i]], 1);
}

__global__ __launch_bounds__(256) void make_norm(const int* __restrict__ deg,
                                                 float* __restrict__ norm, int n) {
    int i = blockIdx.x * 256 + threadIdx.x;
    if (i < n) {
        int d = deg[i];
        norm[i] = rsqrtf((float)(d > 1 ? d : 1));
    }
}

// Single-block exclusive prefix scan of deg[n] -> cursor[n] (bucket starts).
__global__ __launch_bounds__(1024) void scan_deg(const int* __restrict__ deg,
                                                 int* __restrict__ cursor, int n) {
    __shared__ int sums[1024];
    int t = threadIdx.x;
    int per = (n + 1023) / 1024;
    int lo = t * per;
    int hi = lo + per; if (hi > n) hi = n;
    int s = 0;
    for (int i = lo; i < hi; ++i) s += deg[i];
    sums[t] = s;
    __syncthreads();
    // Hillis-Steele inclusive scan over 1024 partials
    for (int off = 1; off < 1024; off <<= 1) {
        int v = (t >= off) ? sums[t - off] : 0;
        __syncthreads();
        sums[t] += v;
        __syncthreads();
    }
    int run = (t == 0) ? 0 : sums[t - 1];
    for (int i = lo; i < hi; ++i) {
        int d = deg[i];
        cursor[i] = run;
        run += d;
    }
}

// After fill, cursor[d] == end of bucket d (== start of bucket d+1).
__global__ __launch_bounds__(256) void bucket_fill(const int* __restrict__ src,
                                                   const int* __restrict__ dst,
                                                   int* __restrict__ cursor,
                                                   int* __restrict__ ebuf, int ne) {
    int e = blockIdx.x * 256 + threadIdx.x;
    if (e < ne) {
        int d = dst[e];
        int slot = atomicAdd(&cursor[d], 1);
        ebuf[slot] = src[e];
    }
}

// W [out=128][in=128] row-major -> Wt[(k>>2)*512 + j*4 + (k&3)] so thread j
// loads float4 {W[j][4k4..4k4+3]} with consecutive-j coalescing.
__global__ __launch_bounds__(256) void transpose_w(const float* __restrict__ W,
                                                   float* __restrict__ Wt) {
    int i = blockIdx.x * 256 + threadIdx.x; // 0..16383
    int j = i >> 7;
    int k = i & 127;
    Wt[(k >> 2) * 512 + j * 4 + (k & 3)] = W[i];
}

// Phase 1: 32-lane group g aggregates node = blockIdx*8+g:
//   acc4 = norm[node] * sum_{e in bucket} norm[src_e] * h[src_e][lane*4..+3]
// into LDS row xs[g]. Phase 2: 8x128 mini-GEMM: thread (j=tid&127, half=tid>>7)
// computes out[r0+r][j] for r=0..3 from LDS broadcasts + coalesced Wt loads.
__global__ __launch_bounds__(256) void gather_gemm(const float* __restrict__ h,
                                                   const int* __restrict__ ebuf,
                                                   const int* __restrict__ cursor,
                                                   const float* __restrict__ norm,
                                                   const float* __restrict__ Wt,
                                                   const float* __restrict__ b,
                                                   float* __restrict__ out, int n) {
    __shared__ float xs[8 * DIM];
    int tid = threadIdx.x;
    int g = tid >> 5, lane = tid & 31;
    int node = blockIdx.x * 8 + g;

    float4 acc = make_float4(0.f, 0.f, 0.f, 0.f);
    if (node < n) {
        int s0 = (node == 0) ? 0 : cursor[node - 1];
        int s1 = cursor[node];
        const float4* h4 = (const float4*)h;
        for (int i = s0; i < s1; ++i) {
            int s = ebuf[i];
            float sc = norm[s];
            float4 v = h4[(size_t)s * 32 + lane];
            acc.x += v.x * sc;
            acc.y += v.y * sc;
            acc.z += v.z * sc;
            acc.w += v.w * sc;
        }
        float nd = norm[node];
        acc.x *= nd; acc.y *= nd; acc.z *= nd; acc.w *= nd;
        *(float4*)(xs + g * DIM + lane * 4) = acc;
    }
    __syncthreads();

    int j = tid & 127, half = tid >> 7;
    const float4* Wt4 = (const float4*)Wt;
    const float4* xs4 = (const float4*)xs;
    float o0 = 0.f, o1 = 0.f, o2 = 0.f, o3 = 0.f;
#pragma unroll 4
    for (int k4 = 0; k4 < 32; ++k4) {
        float4 w = Wt4[k4 * 128 + j]; // coalesced across j
        float4 x0 = xs4[(half * 4 + 0) * 32 + k4]; // wave-uniform -> LDS broadcast
        float4 x1 = xs4[(half * 4 + 1) * 32 + k4];
        float4 x2 = xs4[(half * 4 + 2) * 32 + k4];
        float4 x3 = xs4[(half * 4 + 3) * 32 + k4];
        o0 += x0.x * w.x + x0.y * w.y + x0.z * w.z + x0.w * w.w;
        o1 += x1.x * w.x + x1.y * w.y + x1.z * w.z + x1.w * w.w;
        o2 += x2.x * w.x + x2.y * w.y + x2.z * w.z + x2.w * w.w;
        o3 += x3.x * w.x + x3.y * w.y + x3.z * w.z + x3.w * w.w;
    }
    float bj = b[j];
    int r0 = blockIdx.x * 8 + half * 4;
#pragma unroll
    for (int r = 0; r < 4; ++r) {
        float o = (r == 0) ? o0 : (r == 1) ? o1 : (r == 2) ? o2 : o3;
        if (r0 + r < n) out[(size_t)(r0 + r) * DIM + j] = o + bj;
    }
}

extern "C" void kernel_launch(void* const* d_in, const int* in_sizes, int n_in,
                              void* d_out, int out_size, void* d_ws, size_t ws_size,
                              hipStream_t stream) {
    const float* h = (const float*)d_in[0];  // fp32 [N,128]
    const float* W = (const float*)d_in[1];  // fp32 [128,128]
    const float* b = (const float*)d_in[2];  // fp32 [128]
    const int* esrc = (const int*)d_in[3];
    const int* edst = (const int*)d_in[4];
    float* out = (float*)d_out;              // fp32 [N,128]

    int n = in_sizes[0] / DIM;   // 100000
    int ne = in_sizes[3];        // 1600000

    float* norm = (float*)d_ws;
    float* Wt = norm + n;
    int* deg = (int*)(Wt + DIM * DIM);
    int* cursor = deg + n;
    int* ebuf = cursor + n;

    hipMemsetAsync(deg, 0, (size_t)n * sizeof(int), stream);

    deg_count<<<(ne + 255) / 256, 256, 0, stream>>>(edst, deg, ne);
    make_norm<<<(n + 255) / 256, 256, 0, stream>>>(deg, norm, n);
    scan_deg<<<1, 1024, 0, stream>>>(deg, cursor, n);
    transpose_w<<<64, 256, 0, stream>>>(W, Wt);
    bucket_fill<<<(ne + 255) / 256, 256, 0, stream>>>(esrc, edst, cursor, ebuf, ne);
    gather_gemm<<<(n + 7) / 8, 256, 0, stream>>>(h, ebuf, cursor, norm, Wt, b, out, n);
}

// Round 5
// 420.772 us; speedup vs baseline: 7.3411x; 1.4248x over previous
//
#include <hip/hip_runtime.h>
#include <hip/hip_fp16.h>

#define DIM 128

// ws layout: hn f16[n*128] (25.6MB) | norm f32[n] | Wt f32[16384] | deg i32[n]
//            | cursor i32[n] | bsum i32[128] | ebuf i32[ne]   (~33 MB total)

__global__ __launch_bounds__(256) void deg_count(const int* __restrict__ dst,
                                                 int* __restrict__ deg, int ne) {
    int i = blockIdx.x * 256 + threadIdx.x;
    if (i < ne) atomicAdd(&deg[dst[i]], 1);
}

__global__ __launch_bounds__(256) void make_norm(const int* __restrict__ deg,
                                                 float* __restrict__ norm, int n) {
    int i = blockIdx.x * 256 + threadIdx.x;
    if (i < n) {
        int d = deg[i];
        norm[i] = rsqrtf((float)(d > 1 ? d : 1));
    }
}

// hn[i][k] = (fp16) h[i][k] * norm[i]; one thread per float4 (32 per row)
__global__ __launch_bounds__(256) void hn_pack(const float* __restrict__ h,
                                               const float* __restrict__ norm,
                                               float2* __restrict__ hn, int n32) {
    int i = blockIdx.x * 256 + threadIdx.x;
    if (i >= n32) return;
    float sc = norm[i >> 5];
    float4 v = ((const float4*)h)[i];
    union { __half2 h2[2]; float2 f2; } u;
    u.h2[0] = __floats2half2_rn(v.x * sc, v.y * sc);
    u.h2[1] = __floats2half2_rn(v.z * sc, v.w * sc);
    hn[i] = u.f2;
}

// W [out=128][in=128] row-major -> Wt[(k>>2)*512 + j*4 + (k&3)]
__global__ __launch_bounds__(256) void transpose_w(const float* __restrict__ W,
                                                   float* __restrict__ Wt) {
    int i = blockIdx.x * 256 + threadIdx.x; // 0..16383
    int j = i >> 7;
    int k = i & 127;
    Wt[(k >> 2) * 512 + j * 4 + (k & 3)] = W[i];
}

// --- 3-kernel exclusive scan of deg[n] -> cursor[n] ---
__global__ __launch_bounds__(1024) void scan_a(const int* __restrict__ deg,
                                               int* __restrict__ cursor,
                                               int* __restrict__ bsum, int n) {
    __shared__ int s[1024];
    int t = threadIdx.x;
    int i = blockIdx.x * 1024 + t;
    int d = (i < n) ? deg[i] : 0;
    s[t] = d;
    __syncthreads();
    for (int off = 1; off < 1024; off <<= 1) {
        int v = (t >= off) ? s[t - off] : 0;
        __syncthreads();
        s[t] += v;
        __syncthreads();
    }
    if (i < n) cursor[i] = s[t] - d;           // local exclusive
    if (t == 1023) bsum[blockIdx.x] = s[1023]; // block total
}

__global__ __launch_bounds__(128) void scan_b(int* __restrict__ bsum, int nb) {
    __shared__ int s[128];
    int t = threadIdx.x;
    int d = (t < nb) ? bsum[t] : 0;
    s[t] = d;
    __syncthreads();
    for (int off = 1; off < 128; off <<= 1) {
        int v = (t >= off) ? s[t - off] : 0;
        __syncthreads();
        s[t] += v;
        __syncthreads();
    }
    if (t < nb) bsum[t] = s[t] - d;            // exclusive block offsets
}

__global__ __launch_bounds__(1024) void scan_c(int* __restrict__ cursor,
                                               const int* __restrict__ bsum, int n) {
    int i = blockIdx.x * 1024 + threadIdx.x;
    if (i < n) cursor[i] += bsum[blockIdx.x];
}

// After fill, cursor[d] == end of bucket d.
__global__ __launch_bounds__(256) void bucket_fill(const int* __restrict__ src,
                                                   const int* __restrict__ dst,
                                                   int* __restrict__ cursor,
                                                   int* __restrict__ ebuf, int ne) {
    int e = blockIdx.x * 256 + threadIdx.x;
    if (e < ne) {
        int d = dst[e];
        int slot = atomicAdd(&cursor[d], 1);
        ebuf[slot] = src[e];
    }
}

// Phase 1: 32-lane group g aggregates node = blockIdx*8+g from fp16 hn rows
// (premultiplied by norm[src]); epilogue *norm[node] -> LDS row.
// Phase 2: 8x128 mini-GEMM from LDS broadcasts + coalesced Wt loads.
__global__ __launch_bounds__(256) void gather_gemm(const float2* __restrict__ hn,
                                                   const int* __restrict__ ebuf,
                                                   const int* __restrict__ cursor,
                                                   const float* __restrict__ norm,
                                                   const float* __restrict__ Wt,
                                                   const float* __restrict__ b,
                                                   float* __restrict__ out, int n) {
    __shared__ float xs[8 * DIM];
    int tid = threadIdx.x;
    int g = tid >> 5, lane = tid & 31;
    int node = blockIdx.x * 8 + g;

    if (node < n) {
        float4 acc = make_float4(0.f, 0.f, 0.f, 0.f);
        int s0 = (node == 0) ? 0 : cursor[node - 1];
        int s1 = cursor[node];
        int i = s0;
        // unroll x2: two independent row loads in flight
        for (; i + 1 < s1; i += 2) {
            int sa = ebuf[i];
            int sb = ebuf[i + 1];
            float2 ra = hn[(size_t)sa * 32 + lane];
            float2 rb = hn[(size_t)sb * 32 + lane];
            __half2* pa = (__half2*)&ra;
            __half2* pb = (__half2*)&rb;
            float2 a0 = __half22float2(pa[0]), a1 = __half22float2(pa[1]);
            float2 b0 = __half22float2(pb[0]), b1 = __half22float2(pb[1]);
            acc.x += a0.x + b0.x;
            acc.y += a0.y + b0.y;
            acc.z += a1.x + b1.x;
            acc.w += a1.y + b1.y;
        }
        if (i < s1) {
            int sa = ebuf[i];
            float2 ra = hn[(size_t)sa * 32 + lane];
            __half2* pa = (__half2*)&ra;
            float2 a0 = __half22float2(pa[0]), a1 = __half22float2(pa[1]);
            acc.x += a0.x;
            acc.y += a0.y;
            acc.z += a1.x;
            acc.w += a1.y;
        }
        float nd = norm[node];
        acc.x *= nd; acc.y *= nd; acc.z *= nd; acc.w *= nd;
        *(float4*)(xs + g * DIM + lane * 4) = acc;
    }
    __syncthreads();

    int j = tid & 127, half = tid >> 7;
    const float4* Wt4 = (const float4*)Wt;
    const float4* xs4 = (const float4*)xs;
    float o0 = 0.f, o1 = 0.f, o2 = 0.f, o3 = 0.f;
#pragma unroll 4
    for (int k4 = 0; k4 < 32; ++k4) {
        float4 w = Wt4[k4 * 128 + j]; // coalesced across j
        float4 x0 = xs4[(half * 4 + 0) * 32 + k4]; // wave-uniform LDS broadcast
        float4 x1 = xs4[(half * 4 + 1) * 32 + k4];
        float4 x2 = xs4[(half * 4 + 2) * 32 + k4];
        float4 x3 = xs4[(half * 4 + 3) * 32 + k4];
        o0 += x0.x * w.x + x0.y * w.y + x0.z * w.z + x0.w * w.w;
        o1 += x1.x * w.x + x1.y * w.y + x1.z * w.z + x1.w * w.w;
        o2 += x2.x * w.x + x2.y * w.y + x2.z * w.z + x2.w * w.w;
        o3 += x3.x * w.x + x3.y * w.y + x3.z * w.z + x3.w * w.w;
    }
    float bj = b[j];
    int r0 = blockIdx.x * 8 + half * 4;
#pragma unroll
    for (int r = 0; r < 4; ++r) {
        float o = (r == 0) ? o0 : (r == 1) ? o1 : (r == 2) ? o2 : o3;
        if (r0 + r < n) out[(size_t)(r0 + r) * DIM + j] = o + bj;
    }
}

extern "C" void kernel_launch(void* const* d_in, const int* in_sizes, int n_in,
                              void* d_out, int out_size, void* d_ws, size_t ws_size,
                              hipStream_t stream) {
    const float* h = (const float*)d_in[0];  // fp32 [N,128]
    const float* W = (const float*)d_in[1];  // fp32 [128,128]
    const float* b = (const float*)d_in[2];  // fp32 [128]
    const int* esrc = (const int*)d_in[3];
    const int* edst = (const int*)d_in[4];
    float* out = (float*)d_out;              // fp32 [N,128]

    int n = in_sizes[0] / DIM;   // 100000
    int ne = in_sizes[3];        // 1600000

    float2* hn = (float2*)d_ws;                  // n*32 float2 (fp16x4 packed)
    float* norm = (float*)(hn + (size_t)n * 32);
    float* Wt = norm + n;
    int* deg = (int*)(Wt + DIM * DIM);
    int* cursor = deg + n;
    int* bsum = cursor + n;
    int* ebuf = bsum + 128;

    int nscan = (n + 1023) / 1024; // 98

    hipMemsetAsync(deg, 0, (size_t)n * sizeof(int), stream);

    deg_count<<<(ne + 255) / 256, 256, 0, stream>>>(edst, deg, ne);
    make_norm<<<(n + 255) / 256, 256, 0, stream>>>(deg, norm, n);
    hn_pack<<<(n * 32 + 255) / 256, 256, 0, stream>>>(h, norm, hn, n * 32);
    transpose_w<<<64, 256, 0, stream>>>(W, Wt);
    scan_a<<<nscan, 1024, 0, stream>>>(deg, cursor, bsum, n);
    scan_b<<<1, 128, 0, stream>>>(bsum, nscan);
    scan_c<<<nscan, 1024, 0, stream>>>(cursor, bsum, n);
    bucket_fill<<<(ne + 255) / 256, 256, 0, stream>>>(esrc, edst, cursor, ebuf, ne);
    gather_gemm<<<(n + 7) / 8, 256, 0, stream>>>(hn, ebuf, cursor, norm, Wt, b, out, n);
}

// Round 6
// 336.072 us; speedup vs baseline: 9.1913x; 1.2520x over previous
//
#include <hip/hip_runtime.h>
#include <hip/hip_fp16.h>

#define DIM 128

typedef _Float16 half8_t __attribute__((ext_vector_type(8)));
typedef float f32x4 __attribute__((ext_vector_type(4)));

// ws: hn f16[n*128] (25.6MB) | Wf f16[16384] (32KB) | deg i32[n] | cursor i32[n]
//     | bsum i32[128] | ebuf i32[ne]   (~32.8 MB)

// 4 edges/thread: independent fire-and-forget atomics (4x MLP)
__global__ __launch_bounds__(256) void deg_count(const int* __restrict__ dst,
                                                 int* __restrict__ deg, int ne) {
    int i0 = blockIdx.x * 1024 + threadIdx.x;
#pragma unroll
    for (int u = 0; u < 4; ++u) {
        int i = i0 + u * 256;
        if (i < ne) atomicAdd(&deg[dst[i]], 1);
    }
}

// hn[i][k] = (fp16) h[i][k] * rsqrt(max(deg[i],1)); one thread per float4
__global__ __launch_bounds__(256) void hn_pack(const float* __restrict__ h,
                                               const int* __restrict__ deg,
                                               float2* __restrict__ hn, int n32) {
    int i = blockIdx.x * 256 + threadIdx.x;
    if (i >= n32) return;
    int d = deg[i >> 5];
    float sc = rsqrtf((float)(d > 1 ? d : 1));
    float4 v = ((const float4*)h)[i];
    union { __half2 h2[2]; float2 f2; } u;
    u.h2[0] = __floats2half2_rn(v.x * sc, v.y * sc);
    u.h2[1] = __floats2half2_rn(v.z * sc, v.w * sc);
    hn[i] = u.f2;
}

// Build fp16 B-fragment table for mfma_f32_16x16x32_f16:
// Wf[((tile*4+kk)*64 + lane)*8 + j] = W[tile*16 + (lane&15)][kk*32 + (lane>>4)*8 + j]
__global__ __launch_bounds__(256) void wprep(const float* __restrict__ W,
                                             _Float16* __restrict__ Wf) {
    int idx = blockIdx.x * 256 + threadIdx.x; // 0..2047 = (tile,kk,lane)
    int tile = idx >> 8;
    int kk = (idx >> 6) & 3;
    int lane = idx & 63;
    int nn = lane & 15, quad = lane >> 4;
    const float* wr = W + (tile * 16 + nn) * DIM + kk * 32 + quad * 8;
    _Float16* o = Wf + (size_t)idx * 8;
#pragma unroll
    for (int j = 0; j < 8; ++j) o[j] = (_Float16)wr[j];
}

// local exclusive scan per 1024-chunk; bsum[chunk] = chunk total
__global__ __launch_bounds__(1024) void scan_a(const int* __restrict__ deg,
                                               int* __restrict__ cursor,
                                               int* __restrict__ bsum, int n) {
    __shared__ int s[1024];
    int t = threadIdx.x;
    int i = blockIdx.x * 1024 + t;
    int d = (i < n) ? deg[i] : 0;
    s[t] = d;
    __syncthreads();
    for (int off = 1; off < 1024; off <<= 1) {
        int v = (t >= off) ? s[t - off] : 0;
        __syncthreads();
        s[t] += v;
        __syncthreads();
    }
    if (i < n) cursor[i] = s[t] - d;
    if (t == 1023) bsum[blockIdx.x] = s[1023];
}

__global__ __launch_bounds__(128) void scan_b(int* __restrict__ bsum, int nb) {
    __shared__ int s[128];
    int t = threadIdx.x;
    int d = (t < nb) ? bsum[t] : 0;
    s[t] = d;
    __syncthreads();
    for (int off = 1; off < 128; off <<= 1) {
        int v = (t >= off) ? s[t - off] : 0;
        __syncthreads();
        s[t] += v;
        __syncthreads();
    }
    if (t < nb) bsum[t] = s[t] - d; // exclusive chunk offsets
}

// slot = local_slot(atomic on local cursor) + bsum[d>>10]; 4 edges/thread.
__global__ __launch_bounds__(256) void bucket_fill(const int* __restrict__ src,
                                                   const int* __restrict__ dst,
                                                   int* __restrict__ cursor,
                                                   const int* __restrict__ bsum,
                                                   int* __restrict__ ebuf, int ne) {
    int i0 = blockIdx.x * 1024 + threadIdx.x;
    bool p[4]; int dd[4], ss[4], sl[4];
#pragma unroll
    for (int u = 0; u < 4; ++u) {
        int i = i0 + u * 256;
        p[u] = (i < ne);
        dd[u] = p[u] ? dst[i] : 0;
        ss[u] = p[u] ? src[i] : 0;
    }
#pragma unroll
    for (int u = 0; u < 4; ++u)
        if (p[u]) sl[u] = atomicAdd(&cursor[dd[u]], 1) + bsum[dd[u] >> 10];
#pragma unroll
    for (int u = 0; u < 4; ++u)
        if (p[u]) ebuf[sl[u]] = ss[u];
}

// Phase 1: 16 groups x 32 lanes; group g aggregates node=blk*16+g in packed fp16,
// epilogue *rsqrt(deg[node]) -> fp16 xs row (stride 136 halfs: 2-way banks, free).
// Phase 2: 8 waves; wave w = col-tile w; 4 chained mfma_f32_16x16x32_f16 (K=128);
// A from xs (m=lane&15, k=quad*8+j), B from Wf table, C: col=lane&15, row=quad*4+r.
__global__ __launch_bounds__(512) void gather_gemm(const float2* __restrict__ hn,
                                                   const int* __restrict__ ebuf,
                                                   const int* __restrict__ cursor,
                                                   const int* __restrict__ bsum,
                                                   const int* __restrict__ deg,
                                                   const _Float16* __restrict__ Wf,
                                                   const float* __restrict__ b,
                                                   float* __restrict__ out, int n) {
    __shared__ _Float16 xs[16 * 136];
    int tid = threadIdx.x;
    int g = tid >> 5, lane = tid & 31;
    int node = blockIdx.x * 16 + g;

    if (node < n) {
        int s1 = cursor[node] + bsum[node >> 10];
        int s0 = (node == 0) ? 0 : cursor[node - 1] + bsum[(node - 1) >> 10];
        __half2 a0 = __floats2half2_rn(0.f, 0.f), a1 = a0;
        int i = s0;
        for (; i + 3 < s1; i += 4) { // 4 row loads in flight
            int e0 = ebuf[i], e1 = ebuf[i + 1], e2 = ebuf[i + 2], e3 = ebuf[i + 3];
            float2 r0 = hn[(size_t)e0 * 32 + lane];
            float2 r1 = hn[(size_t)e1 * 32 + lane];
            float2 r2 = hn[(size_t)e2 * 32 + lane];
            float2 r3 = hn[(size_t)e3 * 32 + lane];
            const __half2* q0 = (const __half2*)&r0;
            const __half2* q1 = (const __half2*)&r1;
            const __half2* q2 = (const __half2*)&r2;
            const __half2* q3 = (const __half2*)&r3;
            a0 = __hadd2(a0, q0[0]); a1 = __hadd2(a1, q0[1]);
            a0 = __hadd2(a0, q1[0]); a1 = __hadd2(a1, q1[1]);
            a0 = __hadd2(a0, q2[0]); a1 = __hadd2(a1, q2[1]);
            a0 = __hadd2(a0, q3[0]); a1 = __hadd2(a1, q3[1]);
        }
        for (; i < s1; ++i) {
            int e0 = ebuf[i];
            float2 r0 = hn[(size_t)e0 * 32 + lane];
            const __half2* q0 = (const __half2*)&r0;
            a0 = __hadd2(a0, q0[0]); a1 = __hadd2(a1, q0[1]);
        }
        int dn = deg[node];
        float nd = rsqrtf((float)(dn > 1 ? dn : 1));
        float2 f0 = __half22float2(a0), f1 = __half22float2(a1);
        union { __half2 h2[2]; float2 f2; } u;
        u.h2[0] = __floats2half2_rn(f0.x * nd, f0.y * nd);
        u.h2[1] = __floats2half2_rn(f1.x * nd, f1.y * nd);
        *(float2*)(xs + g * 136 + lane * 4) = u.f2;
    }
    __syncthreads();

    int w = tid >> 6;     // wave = col-tile
    int wl = tid & 63;
    int cn = wl & 15;     // A-row m, B/C col n
    int quad = wl >> 4;

    f32x4 acc = {0.f, 0.f, 0.f, 0.f};
#pragma unroll
    for (int kk = 0; kk < 4; ++kk) {
        half8_t af = *(const half8_t*)(xs + cn * 136 + kk * 32 + quad * 8);
        half8_t bf = ((const half8_t*)Wf)[(w * 4 + kk) * 64 + wl];
        acc = __builtin_amdgcn_mfma_f32_16x16x32_f16(af, bf, acc, 0, 0, 0);
    }
    float bj = b[w * 16 + cn];
    int node0 = blockIdx.x * 16;
#pragma unroll
    for (int r = 0; r < 4; ++r) {
        int row = quad * 4 + r;
        if (node0 + row < n)
            out[(size_t)(node0 + row) * DIM + w * 16 + cn] = acc[r] + bj;
    }
}

extern "C" void kernel_launch(void* const* d_in, const int* in_sizes, int n_in,
                              void* d_out, int out_size, void* d_ws, size_t ws_size,
                              hipStream_t stream) {
    const float* h = (const float*)d_in[0];
    const float* W = (const float*)d_in[1];
    const float* b = (const float*)d_in[2];
    const int* esrc = (const int*)d_in[3];
    const int* edst = (const int*)d_in[4];
    float* out = (float*)d_out;

    int n = in_sizes[0] / DIM;   // 100000
    int ne = in_sizes[3];        // 1600000

    float2* hn = (float2*)d_ws;                       // n*32 float2
    _Float16* Wf = (_Float16*)(hn + (size_t)n * 32);  // 16384 halfs
    int* deg = (int*)(Wf + 16384);
    int* cursor = deg + n;
    int* bsum = cursor + n;
    int* ebuf = bsum + 128;

    int nscan = (n + 1023) / 1024; // 98

    hipMemsetAsync(deg, 0, (size_t)n * sizeof(int), stream);

    deg_count<<<(ne + 1023) / 1024, 256, 0, stream>>>(edst, deg, ne);
    hn_pack<<<(n * 32 + 255) / 256, 256, 0, stream>>>(h, deg, hn, n * 32);
    wprep<<<8, 256, 0, stream>>>(W, Wf);
    scan_a<<<nscan, 1024, 0, stream>>>(deg, cursor, bsum, n);
    scan_b<<<1, 128, 0, stream>>>(bsum, nscan);
    bucket_fill<<<(ne + 1023) / 1024, 256, 0, stream>>>(esrc, edst, cursor, bsum, ebuf, ne);
    gather_gemm<<<(n + 15) / 16, 512, 0, stream>>>(hn, ebuf, cursor, bsum, deg, Wf, b, out, n);
}

// Round 7
// 251.881 us; speedup vs baseline: 12.2635x; 1.3343x over previous
//
#include <hip/hip_runtime.h>
#include <hip/hip_fp16.h>

#define DIM 128
#define TSH 9
#define TSZ 512   // dst-tile size (nodes per tile)

typedef _Float16 half8_t __attribute__((ext_vector_type(8)));
typedef float f32x4 __attribute__((ext_vector_type(4)));

// ws: hn f16[n*128] (25.6MB) | Wf f16[16384] | row_start i32[n+1] |
//     gh i32[nt*nblk] (~1.23MB) | gbsum i32[512] | tbuf u32[ne] | ebuf i32[ne]

// Per-block histogram of dst-tile key -> gh[key*nblk + block]. No global atomics.
__global__ __launch_bounds__(256) void hist_a(const int* __restrict__ dst,
                                              int* __restrict__ gh,
                                              int ne, int nblk, int nt) {
    __shared__ int h[256];
    int t = threadIdx.x;
    h[t] = 0;
    __syncthreads();
    int i0 = blockIdx.x * 1024 + t;
#pragma unroll
    for (int u = 0; u < 4; ++u) {
        int i = i0 + u * 256;
        if (i < ne) atomicAdd(&h[dst[i] >> TSH], 1);
    }
    __syncthreads();
    if (t < nt) gh[t * nblk + blockIdx.x] = h[t];
}

// --- 3-kernel exclusive scan of gh[M] in place ---
__global__ __launch_bounds__(1024) void scan_a(int* __restrict__ g,
                                               int* __restrict__ bsum, int M) {
    __shared__ int s[1024];
    int t = threadIdx.x;
    int i = blockIdx.x * 1024 + t;
    int d = (i < M) ? g[i] : 0;
    s[t] = d;
    __syncthreads();
    for (int off = 1; off < 1024; off <<= 1) {
        int v = (t >= off) ? s[t - off] : 0;
        __syncthreads();
        s[t] += v;
        __syncthreads();
    }
    if (i < M) g[i] = s[t] - d;
    if (t == 1023) bsum[blockIdx.x] = s[1023];
}

__global__ __launch_bounds__(512) void scan_b(int* __restrict__ bsum, int nb) {
    __shared__ int s[512];
    int t = threadIdx.x;
    int d = (t < nb) ? bsum[t] : 0;
    s[t] = d;
    __syncthreads();
    for (int off = 1; off < 512; off <<= 1) {
        int v = (t >= off) ? s[t - off] : 0;
        __syncthreads();
        s[t] += v;
        __syncthreads();
    }
    if (t < nb) bsum[t] = s[t] - d;
}

__global__ __launch_bounds__(1024) void scan_c(int* __restrict__ g,
                                               const int* __restrict__ bsum, int M) {
    int i = blockIdx.x * 1024 + threadIdx.x;
    if (i < M) g[i] += bsum[blockIdx.x];
}

// Re-read edges; LDS-atomic local rank within (block,key); deterministic global
// position ghs[key*nblk + block] + rank. Write packed (src<<9)|dst_local.
__global__ __launch_bounds__(256) void scatter_b(const int* __restrict__ src,
                                                 const int* __restrict__ dst,
                                                 const int* __restrict__ ghs,
                                                 unsigned* __restrict__ tbuf,
                                                 int ne, int nblk) {
    __shared__ int h[256];
    int t = threadIdx.x;
    h[t] = 0;
    __syncthreads();
    int i0 = blockIdx.x * 1024 + t;
#pragma unroll
    for (int u = 0; u < 4; ++u) {
        int i = i0 + u * 256;
        if (i < ne) {
            int d = dst[i];
            int key = d >> TSH;
            int r = atomicAdd(&h[key], 1);
            int pos = ghs[key * nblk + blockIdx.x] + r;
            tbuf[pos] = ((unsigned)src[i] << TSH) | (unsigned)(d & (TSZ - 1));
        }
    }
}

// One block per tile: exact-dst LDS histogram -> LDS scan -> row_start (deg!) ->
// LDS-rank scatter into final dst-sorted ebuf (values = src).
__global__ __launch_bounds__(256) void tile_sort(const unsigned* __restrict__ tbuf,
                                                 const int* __restrict__ ghs,
                                                 int* __restrict__ ebuf,
                                                 int* __restrict__ row_start,
                                                 int n, int ne, int nblk, int nt) {
    __shared__ int hist[TSZ];
    __shared__ int cur[TSZ];
    __shared__ int psum[256];
    int t = threadIdx.x;
    int tile = blockIdx.x;
    int ts = ghs[tile * nblk];
    int te = (tile + 1 < nt) ? ghs[(tile + 1) * nblk] : ne;
    hist[t] = 0;
    hist[t + 256] = 0;
    __syncthreads();
    for (int i = ts + t; i < te; i += 256)
        atomicAdd(&hist[tbuf[i] & (TSZ - 1)], 1);
    __syncthreads();
    // exclusive scan of hist[512] with 256 threads (pairs + Hillis-Steele)
    int a = hist[2 * t], b = hist[2 * t + 1];
    psum[t] = a + b;
    __syncthreads();
    for (int off = 1; off < 256; off <<= 1) {
        int v = (t >= off) ? psum[t - off] : 0;
        __syncthreads();
        psum[t] += v;
        __syncthreads();
    }
    int e0 = psum[t] - a - b; // exclusive prefix at element 2t
    cur[2 * t] = e0;
    cur[2 * t + 1] = e0 + a;
    __syncthreads();
    int node = tile * TSZ + 2 * t;
    if (node <= n) row_start[node] = ts + e0;
    if (node + 1 <= n) row_start[node + 1] = ts + e0 + a;
    for (int i = ts + t; i < te; i += 256) {
        unsigned p = tbuf[i];
        int dl = (int)(p & (TSZ - 1));
        int r = atomicAdd(&cur[dl], 1);
        ebuf[ts + r] = (int)(p >> TSH);
    }
}

// hn[i][k] = (fp16) h[i][k] * rsqrt(max(deg,1)); deg from row_start diff
__global__ __launch_bounds__(256) void hn_pack(const float* __restrict__ h,
                                               const int* __restrict__ rs,
                                               float2* __restrict__ hn, int n32) {
    int i = blockIdx.x * 256 + threadIdx.x;
    if (i >= n32) return;
    int node = i >> 5;
    int d = rs[node + 1] - rs[node];
    float sc = rsqrtf((float)(d > 1 ? d : 1));
    float4 v = ((const float4*)h)[i];
    union { __half2 h2[2]; float2 f2; } u;
    u.h2[0] = __floats2half2_rn(v.x * sc, v.y * sc);
    u.h2[1] = __floats2half2_rn(v.z * sc, v.w * sc);
    hn[i] = u.f2;
}

// Build fp16 B-fragment table for mfma_f32_16x16x32_f16:
// Wf[((tile*4+kk)*64 + lane)*8 + j] = W[tile*16 + (lane&15)][kk*32 + (lane>>4)*8 + j]
__global__ __launch_bounds__(256) void wprep(const float* __restrict__ W,
                                             _Float16* __restrict__ Wf) {
    int idx = blockIdx.x * 256 + threadIdx.x; // 0..2047
    int tile = idx >> 8;
    int kk = (idx >> 6) & 3;
    int lane = idx & 63;
    int nn = lane & 15, quad = lane >> 4;
    const float* wr = W + (tile * 16 + nn) * DIM + kk * 32 + quad * 8;
    _Float16* o = Wf + (size_t)idx * 8;
#pragma unroll
    for (int j = 0; j < 8; ++j) o[j] = (_Float16)wr[j];
}

// Phase 1: 16 groups x 32 lanes aggregate node rows (fp16 packed, x4 unroll);
// Phase 2: 8 waves, wave = col-tile; 4 chained mfma_f32_16x16x32_f16 (K=128).
__global__ __launch_bounds__(512) void gather_gemm(const float2* __restrict__ hn,
                                                   const int* __restrict__ ebuf,
                                                   const int* __restrict__ rs,
                                                   const _Float16* __restrict__ Wf,
                                                   const float* __restrict__ b,
                                                   float* __restrict__ out, int n) {
    __shared__ _Float16 xs[16 * 136];
    int tid = threadIdx.x;
    int g = tid >> 5, lane = tid & 31;
    int node = blockIdx.x * 16 + g;

    if (node < n) {
        int s0 = rs[node];
        int s1 = rs[node + 1];
        __half2 a0 = __floats2half2_rn(0.f, 0.f), a1 = a0;
        int i = s0;
        for (; i + 3 < s1; i += 4) {
            int e0 = ebuf[i], e1 = ebuf[i + 1], e2 = ebuf[i + 2], e3 = ebuf[i + 3];
            float2 r0 = hn[(size_t)e0 * 32 + lane];
            float2 r1 = hn[(size_t)e1 * 32 + lane];
            float2 r2 = hn[(size_t)e2 * 32 + lane];
            float2 r3 = hn[(size_t)e3 * 32 + lane];
            const __half2* q0 = (const __half2*)&r0;
            const __half2* q1 = (const __half2*)&r1;
            const __half2* q2 = (const __half2*)&r2;
            const __half2* q3 = (const __half2*)&r3;
            a0 = __hadd2(a0, q0[0]); a1 = __hadd2(a1, q0[1]);
            a0 = __hadd2(a0, q1[0]); a1 = __hadd2(a1, q1[1]);
            a0 = __hadd2(a0, q2[0]); a1 = __hadd2(a1, q2[1]);
            a0 = __hadd2(a0, q3[0]); a1 = __hadd2(a1, q3[1]);
        }
        for (; i < s1; ++i) {
            int e0 = ebuf[i];
            float2 r0 = hn[(size_t)e0 * 32 + lane];
            const __half2* q0 = (const __half2*)&r0;
            a0 = __hadd2(a0, q0[0]); a1 = __hadd2(a1, q0[1]);
        }
        int dn = s1 - s0;
        float nd = rsqrtf((float)(dn > 1 ? dn : 1));
        float2 f0 = __half22float2(a0), f1 = __half22float2(a1);
        union { __half2 h2[2]; float2 f2; } u;
        u.h2[0] = __floats2half2_rn(f0.x * nd, f0.y * nd);
        u.h2[1] = __floats2half2_rn(f1.x * nd, f1.y * nd);
        *(float2*)(xs + g * 136 + lane * 4) = u.f2;
    }
    __syncthreads();

    int w = tid >> 6;
    int wl = tid & 63;
    int cn = wl & 15;
    int quad = wl >> 4;

    f32x4 acc = {0.f, 0.f, 0.f, 0.f};
#pragma unroll
    for (int kk = 0; kk < 4; ++kk) {
        half8_t af = *(const half8_t*)(xs + cn * 136 + kk * 32 + quad * 8);
        half8_t bf = ((const half8_t*)Wf)[(w * 4 + kk) * 64 + wl];
        acc = __builtin_amdgcn_mfma_f32_16x16x32_f16(af, bf, acc, 0, 0, 0);
    }
    float bj = b[w * 16 + cn];
    int node0 = blockIdx.x * 16;
#pragma unroll
    for (int r = 0; r < 4; ++r) {
        int row = quad * 4 + r;
        if (node0 + row < n)
            out[(size_t)(node0 + row) * DIM + w * 16 + cn] = acc[r] + bj;
    }
}

extern "C" void kernel_launch(void* const* d_in, const int* in_sizes, int n_in,
                              void* d_out, int out_size, void* d_ws, size_t ws_size,
                              hipStream_t stream) {
    const float* h = (const float*)d_in[0];
    const float* W = (const float*)d_in[1];
    const float* b = (const float*)d_in[2];
    const int* esrc = (const int*)d_in[3];
    const int* edst = (const int*)d_in[4];
    float* out = (float*)d_out;

    int n = in_sizes[0] / DIM;   // 100000
    int ne = in_sizes[3];        // 1600000

    int nblk = (ne + 1023) / 1024;        // 1563
    int nt = (n + TSZ - 1) >> TSH;        // 196
    int M = nt * nblk;                    // 306348
    int nsc = (M + 1023) / 1024;          // 300

    float2* hn = (float2*)d_ws;                       // n*32 float2
    _Float16* Wf = (_Float16*)(hn + (size_t)n * 32);  // 16384 halfs
    int* row_start = (int*)(Wf + 16384);              // n+1
    int* gh = row_start + (n + 1);                    // M
    int* gbsum = gh + M;                              // 512
    unsigned* tbuf = (unsigned*)(gbsum + 512);        // ne
    int* ebuf = (int*)(tbuf + ne);                    // ne

    hist_a<<<nblk, 256, 0, stream>>>(edst, gh, ne, nblk, nt);
    scan_a<<<nsc, 1024, 0, stream>>>(gh, gbsum, M);
    scan_b<<<1, 512, 0, stream>>>(gbsum, nsc);
    scan_c<<<nsc, 1024, 0, stream>>>(gh, gbsum, M);
    scatter_b<<<nblk, 256, 0, stream>>>(esrc, edst, gh, tbuf, ne, nblk);
    tile_sort<<<nt, 256, 0, stream>>>(tbuf, gh, ebuf, row_start, n, ne, nblk, nt);
    wprep<<<8, 256, 0, stream>>>(W, Wf);
    hn_pack<<<(n * 32 + 255) / 256, 256, 0, stream>>>(h, row_start, hn, n * 32);
    gather_gemm<<<(n + 15) / 16, 512, 0, stream>>>(hn, ebuf, row_start, Wf, b, out, n);
}

// Round 8
// 233.535 us; speedup vs baseline: 13.2269x; 1.0786x over previous
//
#include <hip/hip_runtime.h>
#include <hip/hip_fp16.h>

#define DIM 128
#define TSH 8
#define TSZ 256    // dst-tile size (nodes per tile)
#define EBLK 4096  // edges per hist/scatter block

typedef _Float16 half8_t __attribute__((ext_vector_type(8)));
typedef float f32x4 __attribute__((ext_vector_type(4)));

// ws: hn f16[n*128] (25.6MB) | Wf f16[16384] | row_start i32[n+1] |
//     gh i32[nt*nblk] (~0.6MB) | gbsum i32[256] | tbuf u32[ne] | ebuf i32[ne]

// Per-block histogram of dst-tile key -> gh[key*nblk + block]. No global atomics.
__global__ __launch_bounds__(256) void hist_a(const int* __restrict__ dst,
                                              int* __restrict__ gh,
                                              int ne, int nblk, int nt) {
    __shared__ int h[512];
    int t = threadIdx.x;
    h[t] = 0; h[t + 256] = 0;
    __syncthreads();
    int i0 = blockIdx.x * EBLK + t;
#pragma unroll
    for (int u = 0; u < 16; ++u) {
        int i = i0 + u * 256;
        if (i < ne) atomicAdd(&h[dst[i] >> TSH], 1);
    }
    __syncthreads();
    for (int k = t; k < nt; k += 256) gh[k * nblk + blockIdx.x] = h[k];
}

// Exclusive scan of gh in 1024-chunks (4 elem/thread, shfl wave-scan);
// bsum[chunk] = chunk total. Chunk offsets folded in later at read sites.
__global__ __launch_bounds__(256) void scan_a(int* __restrict__ g,
                                              int* __restrict__ bsum, int M) {
    __shared__ int wsum[4];
    int t = threadIdx.x;
    int base = blockIdx.x * 1024 + t * 4;
    int4 v;
    if (base + 3 < M) v = *(const int4*)(g + base);
    else {
        v.x = (base + 0 < M) ? g[base + 0] : 0;
        v.y = (base + 1 < M) ? g[base + 1] : 0;
        v.z = (base + 2 < M) ? g[base + 2] : 0;
        v.w = (base + 3 < M) ? g[base + 3] : 0;
    }
    int s3 = v.x + v.y + v.z + v.w;
    int lane = t & 63, wv = t >> 6;
    int x = s3;
#pragma unroll
    for (int off = 1; off < 64; off <<= 1) {
        int y = __shfl_up(x, off, 64);
        if (lane >= off) x += y;
    }
    if (lane == 63) wsum[wv] = x;
    __syncthreads();
    int woff = 0;
    for (int i = 0; i < wv; ++i) woff += wsum[i];
    int ex = woff + x - s3;
    int4 o;
    o.x = ex; o.y = ex + v.x; o.z = o.y + v.y; o.w = o.z + v.z;
    if (base + 3 < M) *(int4*)(g + base) = o;
    else {
        if (base + 0 < M) g[base + 0] = o.x;
        if (base + 1 < M) g[base + 1] = o.y;
        if (base + 2 < M) g[base + 2] = o.z;
        if (base + 3 < M) g[base + 3] = o.w;
    }
    if (t == 0) bsum[blockIdx.x] = wsum[0] + wsum[1] + wsum[2] + wsum[3];
}

// Block 0: exclusive scan of bsum[nb] (nb<=256). Blocks 1..8: build Wf table:
// Wf[((tile*4+kk)*64+lane)*8+j] = W[tile*16+(lane&15)][kk*32+(lane>>4)*8+j]
__global__ __launch_bounds__(256) void scanb_wprep(int* __restrict__ bsum, int nb,
                                                   const float* __restrict__ W,
                                                   _Float16* __restrict__ Wf) {
    if (blockIdx.x == 0) {
        __shared__ int s[256];
        int t = threadIdx.x;
        int d = (t < nb) ? bsum[t] : 0;
        s[t] = d;
        __syncthreads();
        for (int off = 1; off < 256; off <<= 1) {
            int v = (t >= off) ? s[t - off] : 0;
            __syncthreads();
            s[t] += v;
            __syncthreads();
        }
        if (t < nb) bsum[t] = s[t] - d;
    } else {
        int idx = (blockIdx.x - 1) * 256 + threadIdx.x; // 0..2047
        int tile = idx >> 8;
        int kk = (idx >> 6) & 3;
        int lane = idx & 63;
        int nn = lane & 15, quad = lane >> 4;
        const float* wr = W + (tile * 16 + nn) * DIM + kk * 32 + quad * 8;
        _Float16* o = Wf + (size_t)idx * 8;
#pragma unroll
        for (int j = 0; j < 8; ++j) o[j] = (_Float16)wr[j];
    }
}

// Re-read edges; LDS-atomic local rank within (block,key); deterministic global
// position gh[idx]+gb[idx>>10]+rank. Write packed (src<<8)|dst_local.
__global__ __launch_bounds__(256) void scatter_b(const int* __restrict__ src,
                                                 const int* __restrict__ dst,
                                                 const int* __restrict__ gh,
                                                 const int* __restrict__ gb,
                                                 unsigned* __restrict__ tbuf,
                                                 int ne, int nblk) {
    __shared__ int h[512];
    int t = threadIdx.x;
    h[t] = 0; h[t + 256] = 0;
    __syncthreads();
    int i0 = blockIdx.x * EBLK + t;
#pragma unroll
    for (int u = 0; u < 16; ++u) {
        int i = i0 + u * 256;
        if (i < ne) {
            int d = dst[i];
            int key = d >> TSH;
            int r = atomicAdd(&h[key], 1);
            int idx = key * nblk + blockIdx.x;
            int pos = gh[idx] + gb[idx >> 10] + r;
            tbuf[pos] = ((unsigned)src[i] << TSH) | (unsigned)(d & (TSZ - 1));
        }
    }
}

// One block per tile: exact-dst LDS histogram -> LDS scan -> row_start ->
// LDS-rank scatter into final dst-sorted ebuf (values = src).
__global__ __launch_bounds__(256) void tile_sort(const unsigned* __restrict__ tbuf,
                                                 const int* __restrict__ gh,
                                                 const int* __restrict__ gb,
                                                 int* __restrict__ ebuf,
                                                 int* __restrict__ row_start,
                                                 int n, int ne, int nblk, int nt) {
    __shared__ int hist[TSZ];
    __shared__ int cur[TSZ];
    __shared__ int ps[TSZ];
    int t = threadIdx.x;
    int tile = blockIdx.x;
    int i0 = tile * nblk;
    int ts = gh[i0] + gb[i0 >> 10];
    int i1 = (tile + 1) * nblk;
    int te = (tile + 1 < nt) ? gh[i1] + gb[i1 >> 10] : ne;
    hist[t] = 0;
    __syncthreads();
    for (int i = ts + t; i < te; i += 256)
        atomicAdd(&hist[tbuf[i] & (TSZ - 1)], 1);
    __syncthreads();
    int d = hist[t];
    ps[t] = d;
    __syncthreads();
    for (int off = 1; off < 256; off <<= 1) {
        int v = (t >= off) ? ps[t - off] : 0;
        __syncthreads();
        ps[t] += v;
        __syncthreads();
    }
    int ex = ps[t] - d;
    cur[t] = ex;
    int node = tile * TSZ + t;
    if (node <= n) row_start[node] = ts + ex;
    __syncthreads();
    for (int i = ts + t; i < te; i += 256) {
        unsigned p = tbuf[i];
        int dl = (int)(p & (TSZ - 1));
        int r = atomicAdd(&cur[dl], 1);
        ebuf[ts + r] = (int)(p >> TSH);
    }
}

// hn[i][k] = (fp16) h[i][k] * rsqrt(max(deg,1)); deg from row_start diff
__global__ __launch_bounds__(256) void hn_pack(const float* __restrict__ h,
                                               const int* __restrict__ rs,
                                               float2* __restrict__ hn, int n32) {
    int i = blockIdx.x * 256 + threadIdx.x;
    if (i >= n32) return;
    int node = i >> 5;
    int d = rs[node + 1] - rs[node];
    float sc = rsqrtf((float)(d > 1 ? d : 1));
    float4 v = ((const float4*)h)[i];
    union { __half2 h2[2]; float2 f2; } u;
    u.h2[0] = __floats2half2_rn(v.x * sc, v.y * sc);
    u.h2[1] = __floats2half2_rn(v.z * sc, v.w * sc);
    hn[i] = u.f2;
}

// Phase 1: 16 groups x 32 lanes; group g aggregates 4 nodes {blk*64+it*16+g}
// (degree averaging over 4 draws -> balanced barrier), x8-unrolled loads.
// Phase 2: 8 waves; wave w = col-tile; 4 row-tiles x 4 chained
// mfma_f32_16x16x32_f16 (K=128), bf reused across row-tiles.
__global__ __launch_bounds__(512) void gather_gemm(const float2* __restrict__ hn,
                                                   const int* __restrict__ ebuf,
                                                   const int* __restrict__ rs,
                                                   const _Float16* __restrict__ Wf,
                                                   const float* __restrict__ b,
                                                   float* __restrict__ out, int n) {
    __shared__ _Float16 xs[64 * 136];
    int tid = threadIdx.x;
    int g = tid >> 5, lane = tid & 31;

#pragma unroll
    for (int it = 0; it < 4; ++it) {
        int row = it * 16 + g;
        int node = blockIdx.x * 64 + row;
        union { __half2 h2[2]; float2 f2; } u;
        if (node < n) {
            int s0 = rs[node];
            int s1 = rs[node + 1];
            __half2 a0 = __floats2half2_rn(0.f, 0.f), a1 = a0;
            int i = s0;
            for (; i + 7 < s1; i += 8) {
                int e0 = ebuf[i], e1 = ebuf[i + 1], e2 = ebuf[i + 2], e3 = ebuf[i + 3];
                int e4 = ebuf[i + 4], e5 = ebuf[i + 5], e6 = ebuf[i + 6], e7 = ebuf[i + 7];
                float2 r0 = hn[(size_t)e0 * 32 + lane];
                float2 r1 = hn[(size_t)e1 * 32 + lane];
                float2 r2 = hn[(size_t)e2 * 32 + lane];
                float2 r3 = hn[(size_t)e3 * 32 + lane];
                float2 r4 = hn[(size_t)e4 * 32 + lane];
                float2 r5 = hn[(size_t)e5 * 32 + lane];
                float2 r6 = hn[(size_t)e6 * 32 + lane];
                float2 r7 = hn[(size_t)e7 * 32 + lane];
                const __half2* q0 = (const __half2*)&r0;
                const __half2* q1 = (const __half2*)&r1;
                const __half2* q2 = (const __half2*)&r2;
                const __half2* q3 = (const __half2*)&r3;
                const __half2* q4 = (const __half2*)&r4;
                const __half2* q5 = (const __half2*)&r5;
                const __half2* q6 = (const __half2*)&r6;
                const __half2* q7 = (const __half2*)&r7;
                a0 = __hadd2(a0, q0[0]); a1 = __hadd2(a1, q0[1]);
                a0 = __hadd2(a0, q1[0]); a1 = __hadd2(a1, q1[1]);
                a0 = __hadd2(a0, q2[0]); a1 = __hadd2(a1, q2[1]);
                a0 = __hadd2(a0, q3[0]); a1 = __hadd2(a1, q3[1]);
                a0 = __hadd2(a0, q4[0]); a1 = __hadd2(a1, q4[1]);
                a0 = __hadd2(a0, q5[0]); a1 = __hadd2(a1, q5[1]);
                a0 = __hadd2(a0, q6[0]); a1 = __hadd2(a1, q6[1]);
                a0 = __hadd2(a0, q7[0]); a1 = __hadd2(a1, q7[1]);
            }
            for (; i + 3 < s1; i += 4) {
                int e0 = ebuf[i], e1 = ebuf[i + 1], e2 = ebuf[i + 2], e3 = ebuf[i + 3];
                float2 r0 = hn[(size_t)e0 * 32 + lane];
                float2 r1 = hn[(size_t)e1 * 32 + lane];
                float2 r2 = hn[(size_t)e2 * 32 + lane];
                float2 r3 = hn[(size_t)e3 * 32 + lane];
                const __half2* q0 = (const __half2*)&r0;
                const __half2* q1 = (const __half2*)&r1;
                const __half2* q2 = (const __half2*)&r2;
                const __half2* q3 = (const __half2*)&r3;
                a0 = __hadd2(a0, q0[0]); a1 = __hadd2(a1, q0[1]);
                a0 = __hadd2(a0, q1[0]); a1 = __hadd2(a1, q1[1]);
                a0 = __hadd2(a0, q2[0]); a1 = __hadd2(a1, q2[1]);
                a0 = __hadd2(a0, q3[0]); a1 = __hadd2(a1, q3[1]);
            }
            for (; i < s1; ++i) {
                int e0 = ebuf[i];
                float2 r0 = hn[(size_t)e0 * 32 + lane];
                const __half2* q0 = (const __half2*)&r0;
                a0 = __hadd2(a0, q0[0]); a1 = __hadd2(a1, q0[1]);
            }
            int dn = s1 - s0;
            float nd = rsqrtf((float)(dn > 1 ? dn : 1));
            float2 f0 = __half22float2(a0), f1 = __half22float2(a1);
            u.h2[0] = __floats2half2_rn(f0.x * nd, f0.y * nd);
            u.h2[1] = __floats2half2_rn(f1.x * nd, f1.y * nd);
        } else {
            u.h2[0] = __floats2half2_rn(0.f, 0.f);
            u.h2[1] = u.h2[0];
        }
        *(float2*)(xs + row * 136 + lane * 4) = u.f2;
    }
    __syncthreads();

    int w = tid >> 6;     // wave = col-tile
    int wl = tid & 63;
    int cn = wl & 15;
    int quad = wl >> 4;

    f32x4 acc[4] = {{0.f, 0.f, 0.f, 0.f}, {0.f, 0.f, 0.f, 0.f},
                    {0.f, 0.f, 0.f, 0.f}, {0.f, 0.f, 0.f, 0.f}};
#pragma unroll
    for (int kk = 0; kk < 4; ++kk) {
        half8_t bf = ((const half8_t*)Wf)[(w * 4 + kk) * 64 + wl];
#pragma unroll
        for (int rt = 0; rt < 4; ++rt) {
            half8_t af = *(const half8_t*)(xs + (rt * 16 + cn) * 136 + kk * 32 + quad * 8);
            acc[rt] = __builtin_amdgcn_mfma_f32_16x16x32_f16(af, bf, acc[rt], 0, 0, 0);
        }
    }
    float bj = b[w * 16 + cn];
    int node0 = blockIdx.x * 64;
#pragma unroll
    for (int rt = 0; rt < 4; ++rt) {
#pragma unroll
        for (int r = 0; r < 4; ++r) {
            int node = node0 + rt * 16 + quad * 4 + r;
            if (node < n)
                out[(size_t)node * DIM + w * 16 + cn] = acc[rt][r] + bj;
        }
    }
}

extern "C" void kernel_launch(void* const* d_in, const int* in_sizes, int n_in,
                              void* d_out, int out_size, void* d_ws, size_t ws_size,
                              hipStream_t stream) {
    const float* h = (const float*)d_in[0];
    const float* W = (const float*)d_in[1];
    const float* b = (const float*)d_in[2];
    const int* esrc = (const int*)d_in[3];
    const int* edst = (const int*)d_in[4];
    float* out = (float*)d_out;

    int n = in_sizes[0] / DIM;   // 100000
    int ne = in_sizes[3];        // 1600000

    int nblk = (ne + EBLK - 1) / EBLK;    // 391
    int nt = (n + TSZ - 1) >> TSH;        // 391
    int M = nt * nblk;                    // 152881
    int nsc = (M + 1023) / 1024;          // 150

    float2* hn = (float2*)d_ws;                       // n*32 float2
    _Float16* Wf = (_Float16*)(hn + (size_t)n * 32);  // 16384 halfs
    int* row_start = (int*)(Wf + 16384);              // n+1
    int* gh = row_start + (n + 1);                    // M
    int* gbsum = gh + M;                              // 256
    unsigned* tbuf = (unsigned*)(gbsum + 256);        // ne
    int* ebuf = (int*)(tbuf + ne);                    // ne

    hist_a<<<nblk, 256, 0, stream>>>(edst, gh, ne, nblk, nt);
    scan_a<<<nsc, 256, 0, stream>>>(gh, gbsum, M);
    scanb_wprep<<<9, 256, 0, stream>>>(gbsum, nsc, W, Wf);
    scatter_b<<<nblk, 256, 0, stream>>>(esrc, edst, gh, gbsum, tbuf, ne, nblk);
    tile_sort<<<nt, 256, 0, stream>>>(tbuf, gh, gbsum, ebuf, row_start, n, ne, nblk, nt);
    hn_pack<<<(n * 32 + 255) / 256, 256, 0, stream>>>(h, row_start, hn, n * 32);
    gather_gemm<<<(n + 63) / 64, 512, 0, stream>>>(hn, ebuf, row_start, Wf, b, out, n);
}